// Round 1
// baseline (4065.007 us; speedup 1.0000x reference)
//
#include <hip/hip_runtime.h>
#include <math.h>

#define DD 12
#define D2 144
#define D3 1728
#define D4 20736
#define BB 1024

typedef float2 c32;

__device__ __forceinline__ c32 cmul(c32 a, c32 b) {
  return make_float2(a.x * b.x - a.y * b.y, a.x * b.y + a.y * b.x);
}
__device__ __forceinline__ c32 cfma(c32 a, c32 b, c32 acc) {
  acc.x = fmaf(a.x, b.x, fmaf(-a.y, b.y, acc.x));
  acc.y = fmaf(a.x, b.y, fmaf(a.y, b.x, acc.y));
  return acc;
}

// sector offsets: secoff[N] = sum_{n<N} sz(n)^2, sz(n)=min(n,22-n,11)+1
__constant__ int d_secoff[23] = {0,1,5,14,30,55,91,140,204,285,385,506,650,
                                 771,871,952,1016,1065,1101,1126,1142,1151,1155};

// ---------------- small matrix expm (LDS, 64-thread block) ----------------
__device__ void small_expm(c32* A, c32* S, c32* P, c32* T, float* red, int sz, int tid) {
  const int n2 = sz * sz;
  if (tid < sz) {
    float s = 0.f;
    for (int j = 0; j < sz; ++j) { c32 v = A[tid * sz + j]; s += sqrtf(fmaf(v.x, v.x, v.y * v.y)); }
    red[tid] = s;
  }
  __syncthreads();
  float nrm = 0.f;
  for (int i = 0; i < sz; ++i) nrm = fmaxf(nrm, red[i]);
  int sp = 0;
  while (nrm > 0.35f && sp < 24) { nrm *= 0.5f; ++sp; }
  const float scale = ldexpf(1.f, -sp);
  for (int e = tid; e < n2; e += 64) { A[e].x *= scale; A[e].y *= scale; }
  __syncthreads();
  for (int e = tid; e < n2; e += 64) {
    c32 a = A[e];
    P[e] = a;
    if ((e / sz) == (e % sz)) a.x += 1.f;
    S[e] = a;
  }
  __syncthreads();
  for (int k = 2; k <= 12; ++k) {
    const float inv = 1.f / (float)k;
    for (int e = tid; e < n2; e += 64) {
      int i = e / sz, j = e - i * sz;
      c32 acc = make_float2(0.f, 0.f);
      for (int q = 0; q < sz; ++q) acc = cfma(P[i * sz + q], A[q * sz + j], acc);
      acc.x *= inv; acc.y *= inv;
      T[e] = acc;
    }
    __syncthreads();
    for (int e = tid; e < n2; e += 64) {
      c32 t = T[e];
      P[e] = t;
      S[e].x += t.x; S[e].y += t.y;
    }
    __syncthreads();
  }
  for (int q = 0; q < sp; ++q) {
    for (int e = tid; e < n2; e += 64) {
      int i = e / sz, j = e - i * sz;
      c32 acc = make_float2(0.f, 0.f);
      for (int w = 0; w < sz; ++w) acc = cfma(S[i * sz + w], S[w * sz + j], acc);
      T[e] = acc;
    }
    __syncthreads();
    for (int e = tid; e < n2; e += 64) S[e] = T[e];
    __syncthreads();
  }
}

// ---------------- prep: per-batch displacement encoding (store col 0) ----------------
__global__ __launch_bounds__(64) void prep_disp(const float* __restrict__ x, c32* __restrict__ c0) {
  __shared__ c32 A[144], S[144], P[144], T[144];
  __shared__ float red[12];
  const int tid = threadIdx.x;
  const int b = blockIdx.x >> 2, m = blockIdx.x & 3;
  const float rr = x[b * 8 + m], ph = x[b * 8 + 4 + m];
  float sn, cs;
  sincosf(ph, &sn, &cs);
  const c32 alpha = make_float2(rr * cs, rr * sn);
  for (int e = tid; e < 144; e += 64) A[e] = make_float2(0.f, 0.f);
  __syncthreads();
  if (tid < 11) {
    float sq = sqrtf((float)(tid + 1));
    A[(tid + 1) * 12 + tid] = make_float2(alpha.x * sq, alpha.y * sq);   // alpha * adag
    A[tid * 12 + tid + 1] = make_float2(-alpha.x * sq, alpha.y * sq);    // -conj(alpha) * a
  }
  __syncthreads();
  small_expm(A, S, P, T, red, 12, tid);
  if (tid < 12) c0[(size_t)blockIdx.x * 12 + tid] = S[tid * 12];  // column 0
}

// ---------------- prep: beamsplitter sector blocks ----------------
__global__ __launch_bounds__(64) void prep_bs(const float* __restrict__ th1, const float* __restrict__ ph1,
                                              const float* __restrict__ th2, const float* __restrict__ ph2,
                                              c32* __restrict__ BS) {
  __shared__ c32 A[144], S[144], P[144], T[144];
  __shared__ float red[12];
  const int tid = threadIdx.x;
  const int g = blockIdx.x / 23, N = blockIdx.x % 23;
  const int l = g / 12, rem = g % 12, w = rem / 6, gi = rem % 6;
  const float th = (w ? th2 : th1)[l * 6 + gi];
  const float ph = (w ? ph2 : ph1)[l * 6 + gi];
  const int lo = (N > 11) ? (N - 11) : 0;
  const int sz = (N <= 11) ? (N + 1) : (23 - N);
  float sn, cs;
  sincosf(ph, &sn, &cs);
  for (int e = tid; e < sz * sz; e += 64) A[e] = make_float2(0.f, 0.f);
  __syncthreads();
  if (tid + 1 < sz) {
    int t = tid + 1;
    float s1 = th * sqrtf((float)((lo + t) * (N - lo - t + 1)));
    A[(t - 1) * sz + t] = make_float2(cs * s1, sn * s1);       //  th e^{i ph} sqrt(...)
    A[t * sz + t - 1] = make_float2(-cs * s1, sn * s1);        // -th e^{-i ph} sqrt(...)
  }
  __syncthreads();
  small_expm(A, S, P, T, red, sz, tid);
  c32* dst = BS + (size_t)g * 1156 + d_secoff[N];
  for (int e = tid; e < sz * sz; e += 64) dst[e] = S[e];
}

// ---------------- prep: per-mode composites P1 = S*R1, P2 = K*Disp*R2 ----------------
__global__ __launch_bounds__(64) void prep_p(const float* __restrict__ r_, const float* __restrict__ phir,
                                             const float* __restrict__ vphi1,
                                             const float* __restrict__ a_, const float* __restrict__ phia,
                                             const float* __restrict__ vphi2, const float* __restrict__ kk,
                                             c32* __restrict__ P1, c32* __restrict__ P2) {
  __shared__ c32 A[144], S[144], P[144], T[144];
  __shared__ float red[12];
  const int tid = threadIdx.x;
  const int which = blockIdx.x >> 3, lm = blockIdx.x & 7;
  for (int e = tid; e < 144; e += 64) A[e] = make_float2(0.f, 0.f);
  __syncthreads();
  if (which == 0) {
    const float rv = r_[lm], pv = phir[lm];
    float sn, cs;
    sincosf(pv, &sn, &cs);
    const c32 z = make_float2(rv * cs, rv * sn);
    if (tid < 10) {
      float sq = 0.5f * sqrtf((float)((tid + 1) * (tid + 2)));
      A[tid * 12 + tid + 2] = make_float2(z.x * sq, -z.y * sq);      // 0.5 conj(z) a^2
      A[(tid + 2) * 12 + tid] = make_float2(-z.x * sq, -z.y * sq);   // -0.5 z (a^2)^dag
    }
  } else {
    const float av = a_[lm], pv = phia[lm];
    float sn, cs;
    sincosf(pv, &sn, &cs);
    const c32 alpha = make_float2(av * cs, av * sn);
    if (tid < 11) {
      float sq = sqrtf((float)(tid + 1));
      A[(tid + 1) * 12 + tid] = make_float2(alpha.x * sq, alpha.y * sq);
      A[tid * 12 + tid + 1] = make_float2(-alpha.x * sq, alpha.y * sq);
    }
  }
  __syncthreads();
  small_expm(A, S, P, T, red, 12, tid);
  if (which == 0) {
    const float vp = vphi1[lm];
    for (int e = tid; e < 144; e += 64) {
      int j = e % 12;
      float sn, cs;
      sincosf(vp * (float)j, &sn, &cs);
      P1[(size_t)lm * 144 + e] = cmul(S[e], make_float2(cs, sn));
    }
  } else {
    const float vp = vphi2[lm], kv = kk[lm];
    for (int e = tid; e < 144; e += 64) {
      int i = e / 12, j = e % 12;
      float sn1, cs1, sn2, cs2;
      sincosf(vp * (float)j, &sn1, &cs1);
      float ang = kv * (float)i;  // match reference f32 eval order (k*n)*n
      ang *= (float)i;
      sincosf(ang, &sn2, &cs2);
      P2[(size_t)lm * 144 + e] = cmul(make_float2(cs2, sn2), cmul(S[e], make_float2(cs1, sn1)));
    }
  }
}

// ---------------- init: product state from displacement columns ----------------
__global__ __launch_bounds__(256) void init_psi(c32* __restrict__ psi, const c32* __restrict__ c0) {
  __shared__ c32 v[4][12];
  __shared__ c32 v01[144], v23[144];
  const int b = blockIdx.x, tid = threadIdx.x;
  if (tid < 48) v[tid / 12][tid % 12] = c0[(size_t)b * 48 + tid];
  __syncthreads();
  for (int e = tid; e < 144; e += 256) {
    v01[e] = cmul(v[0][e / 12], v[1][e % 12]);
    v23[e] = cmul(v[2][e / 12], v[3][e % 12]);
  }
  __syncthreads();
  c32* dst = psi + (size_t)b * D4;
  for (int e = tid; e < D4; e += 256) dst[e] = cmul(v01[e / 144], v23[e % 144]);
}

// ---------------- fused pass over modes {1,2,3}: BS(2,3) -> BS(1,2) -> U1 -> U2 -> U3 ----------------
__global__ __launch_bounds__(256) void k123_kernel(
    c32* __restrict__ psi,
    const c32* __restrict__ gbs23, const c32* __restrict__ gbs12,
    const c32* __restrict__ gu1, const c32* __restrict__ gu2, const c32* __restrict__ gu3) {
  __shared__ c32 bufA[D3];
  __shared__ c32 bufB[D3];
  __shared__ c32 gate[2744];  // bs23@0, bs12@1156, u1@2312, u2@2456, u3@2600
  const int tid = threadIdx.x;
  if (gbs23) for (int e = tid; e < 1156; e += 256) gate[e] = gbs23[e];
  if (gbs12) for (int e = tid; e < 1156; e += 256) gate[1156 + e] = gbs12[e];
  if (gu1)   for (int e = tid; e < 144; e += 256) gate[2312 + e] = gu1[e];
  if (gu2)   for (int e = tid; e < 144; e += 256) gate[2456 + e] = gu2[e];
  if (gu3)   for (int e = tid; e < 144; e += 256) gate[2600 + e] = gu3[e];
  c32* slab = psi + (size_t)blockIdx.x * D3;
  {
    const float4* s4 = (const float4*)slab;
    float4* d4 = (float4*)bufA;
    for (int v = tid; v < D3 / 2; v += 256) d4[v] = s4[v];
  }
  __syncthreads();
  c32* cur = bufA;
  c32* nxt = bufB;
  if (gbs23) {
    for (int e = tid; e < D3; e += 256) {
      int n1 = e / 144, r = e - n1 * 144, i = r / 12, j = r - i * 12;
      int N = i + j, lo = (N > 11) ? (N - 11) : 0, sz = (N <= 11) ? (N + 1) : (23 - N);
      const c32* g = gate + (d_secoff[N] + (i - lo) * sz);
      const c32* in = cur + (n1 * 144 + lo * 12 + (N - lo));
      c32 acc = make_float2(0.f, 0.f);
      for (int t = 0; t < sz; ++t) acc = cfma(g[t], in[t * 11], acc);
      nxt[e] = acc;
    }
    __syncthreads();
    c32* tmp = cur; cur = nxt; nxt = tmp;
  }
  if (gbs12) {
    for (int e = tid; e < D3; e += 256) {
      int i = e / 144, r = e - i * 144, j = r / 12, n3 = r - j * 12;
      int N = i + j, lo = (N > 11) ? (N - 11) : 0, sz = (N <= 11) ? (N + 1) : (23 - N);
      const c32* g = gate + (1156 + d_secoff[N] + (i - lo) * sz);
      const c32* in = cur + (lo * 144 + (N - lo) * 12 + n3);
      c32 acc = make_float2(0.f, 0.f);
      for (int t = 0; t < sz; ++t) acc = cfma(g[t], in[t * 132], acc);
      nxt[e] = acc;
    }
    __syncthreads();
    c32* tmp = cur; cur = nxt; nxt = tmp;
  }
  if (gu1) {
    for (int e = tid; e < D3; e += 256) {
      int i = e / 144, r = e - i * 144;
      c32 acc = make_float2(0.f, 0.f);
#pragma unroll
      for (int j = 0; j < 12; ++j) acc = cfma(gate[2312 + i * 12 + j], cur[j * 144 + r], acc);
      nxt[e] = acc;
    }
    __syncthreads();
    c32* tmp = cur; cur = nxt; nxt = tmp;
  }
  if (gu2) {
    for (int e = tid; e < D3; e += 256) {
      int n1 = e / 144, r = e - n1 * 144, i = r / 12, n3 = r - i * 12;
      c32 acc = make_float2(0.f, 0.f);
#pragma unroll
      for (int j = 0; j < 12; ++j) acc = cfma(gate[2456 + i * 12 + j], cur[n1 * 144 + j * 12 + n3], acc);
      nxt[e] = acc;
    }
    __syncthreads();
    c32* tmp = cur; cur = nxt; nxt = tmp;
  }
  if (gu3) {
    for (int e = tid; e < D3; e += 256) {
      int rr = e / 12, i = e - rr * 12;
      c32 acc = make_float2(0.f, 0.f);
#pragma unroll
      for (int j = 0; j < 12; ++j) acc = cfma(gate[2600 + i * 12 + j], cur[rr * 12 + j], acc);
      nxt[e] = acc;
    }
    __syncthreads();
    c32* tmp = cur; cur = nxt; nxt = tmp;
  }
  {
    float4* d4 = (float4*)slab;
    const float4* s4 = (const float4*)cur;
    for (int v = tid; v < D3 / 2; v += 256) d4[v] = s4[v];
  }
}

// ---------------- fused pass over modes {0,1}: U0 -> BS(0,1); tile = 144 rows x 16 inner cols ----------------
__global__ __launch_bounds__(256) void k01_kernel(
    c32* __restrict__ psi, const c32* __restrict__ gu0, const c32* __restrict__ gbs) {
  __shared__ c32 bufA[D2 * 16];
  __shared__ c32 bufB[D2 * 16];
  __shared__ c32 gate[1300];  // bs@0, u0@1156
  const int tid = threadIdx.x;
  if (gbs) for (int e = tid; e < 1156; e += 256) gate[e] = gbs[e];
  if (gu0) for (int e = tid; e < 144; e += 256) gate[1156 + e] = gu0[e];
  const int b = blockIdx.x / 9, tile = blockIdx.x % 9;
  c32* gbase = psi + (size_t)b * D4 + tile * 16;
  {
    float4* d4 = (float4*)bufA;
    for (int e = tid; e < D2 * 8; e += 256) {
      int rrow = e >> 3, q = e & 7;
      d4[e] = ((const float4*)(gbase + (size_t)rrow * 144))[q];
    }
  }
  __syncthreads();
  c32* cur = bufA;
  c32* nxt = bufB;
  if (gu0) {
    for (int e = tid; e < D2 * 16; e += 256) {
      int c = e & 15, rrow = e >> 4, i = rrow / 12, n1 = rrow - i * 12;
      c32 acc = make_float2(0.f, 0.f);
#pragma unroll
      for (int j = 0; j < 12; ++j) acc = cfma(gate[1156 + i * 12 + j], cur[(j * 12 + n1) * 16 + c], acc);
      nxt[e] = acc;
    }
    __syncthreads();
    c32* tmp = cur; cur = nxt; nxt = tmp;
  }
  if (gbs) {
    for (int e = tid; e < D2 * 16; e += 256) {
      int c = e & 15, rrow = e >> 4, i = rrow / 12, j = rrow - i * 12;
      int N = i + j, lo = (N > 11) ? (N - 11) : 0, sz = (N <= 11) ? (N + 1) : (23 - N);
      const c32* g = gate + (d_secoff[N] + (i - lo) * sz);
      const c32* in = cur + (lo * 12 + (N - lo)) * 16 + c;
      c32 acc = make_float2(0.f, 0.f);
      for (int t = 0; t < sz; ++t) acc = cfma(g[t], in[t * 176], acc);
      nxt[e] = acc;
    }
    __syncthreads();
    c32* tmp = cur; cur = nxt; nxt = tmp;
  }
  {
    const float4* s4 = (const float4*)cur;
    for (int e = tid; e < D2 * 8; e += 256) {
      int rrow = e >> 3, q = e & 7;
      ((float4*)(gbase + (size_t)rrow * 144))[q] = s4[e];
    }
  }
}

// ---------------- expvals: <X_m> = sum 2*sqrt(n+1)*Re(conj(psi_n) psi_{n+1}) ----------------
__global__ __launch_bounds__(256) void expval_kernel(const c32* __restrict__ psi, float* __restrict__ out) {
  __shared__ float red[1024];
  __shared__ float sq2[12];
  const int tid = threadIdx.x, b = blockIdx.x;
  if (tid < 12) sq2[tid] = 2.f * sqrtf((float)(tid + 1));
  __syncthreads();
  const c32* base = psi + (size_t)b * D4;
  float a0 = 0.f, a1 = 0.f, a2 = 0.f, a3 = 0.f;
  for (int e = tid; e < D4; e += 256) {
    c32 p = base[e];
    int n3 = e % 12, t = e / 12;
    int n2 = t % 12; t /= 12;
    int n1 = t % 12, n0 = t / 12;
    if (n3 < 11) { c32 q = base[e + 1];    a3 = fmaf(sq2[n3], fmaf(p.x, q.x, p.y * q.y), a3); }
    if (n2 < 11) { c32 q = base[e + 12];   a2 = fmaf(sq2[n2], fmaf(p.x, q.x, p.y * q.y), a2); }
    if (n1 < 11) { c32 q = base[e + 144];  a1 = fmaf(sq2[n1], fmaf(p.x, q.x, p.y * q.y), a1); }
    if (n0 < 11) { c32 q = base[e + 1728]; a0 = fmaf(sq2[n0], fmaf(p.x, q.x, p.y * q.y), a0); }
  }
  red[tid * 4 + 0] = a0; red[tid * 4 + 1] = a1; red[tid * 4 + 2] = a2; red[tid * 4 + 3] = a3;
  __syncthreads();
  for (int s = 128; s > 0; s >>= 1) {
    if (tid < s) {
      red[tid * 4 + 0] += red[(tid + s) * 4 + 0];
      red[tid * 4 + 1] += red[(tid + s) * 4 + 1];
      red[tid * 4 + 2] += red[(tid + s) * 4 + 2];
      red[tid * 4 + 3] += red[(tid + s) * 4 + 3];
    }
    __syncthreads();
  }
  if (tid < 4) out[b * 4 + tid] = red[tid];
}

extern "C" void kernel_launch(void* const* d_in, const int* in_sizes, int n_in,
                              void* d_out, int out_size, void* d_ws, size_t ws_size,
                              hipStream_t stream) {
  const float* x      = (const float*)d_in[0];
  const float* theta1 = (const float*)d_in[1];
  const float* phi1   = (const float*)d_in[2];
  const float* vphi1  = (const float*)d_in[3];
  const float* r_     = (const float*)d_in[4];
  const float* phir   = (const float*)d_in[5];
  const float* theta2 = (const float*)d_in[6];
  const float* phi2   = (const float*)d_in[7];
  const float* vphi2  = (const float*)d_in[8];
  const float* a_     = (const float*)d_in[9];
  const float* phia   = (const float*)d_in[10];
  const float* kk     = (const float*)d_in[11];
  float* out = (float*)d_out;

  // workspace layout (bytes)
  const size_t PSI_OFF = 0;                              // 1024*20736*8 = 169,869,312
  const size_t C0_OFF  = 169869312;                      // 1024*4*12*8  =     393,216
  const size_t P1_OFF  = C0_OFF + 393216;                // 8*144*8      =       9,216
  const size_t P2_OFF  = P1_OFF + 9216;
  const size_t BS_OFF  = P2_OFF + 9216;                  // 24*1156*8    =     221,952
  const size_t NEED    = BS_OFF + 221952;
  if (ws_size < NEED) return;  // insufficient scratch; fail loudly in validation

  char* ws = (char*)d_ws;
  c32* psi = (c32*)(ws + PSI_OFF);
  c32* c0  = (c32*)(ws + C0_OFF);
  c32* P1  = (c32*)(ws + P1_OFF);
  c32* P2  = (c32*)(ws + P2_OFF);
  c32* BS  = (c32*)(ws + BS_OFF);

  prep_disp<<<dim3(4096), dim3(64), 0, stream>>>(x, c0);
  prep_bs<<<dim3(552), dim3(64), 0, stream>>>(theta1, phi1, theta2, phi2, BS);
  prep_p<<<dim3(16), dim3(64), 0, stream>>>(r_, phir, vphi1, a_, phia, vphi2, kk, P1, P2);
  init_psi<<<dim3(1024), dim3(256), 0, stream>>>(psi, c0);

  for (int l = 0; l < 2; ++l) {
    c32* bsl = BS + (size_t)l * 12 * 1156;
    const c32* u0pre = (l == 0) ? (const c32*)nullptr : (const c32*)(P2 + (size_t)(l - 1) * 4 * 144);
    // interferometer 1: BS order per Clements mesh: (0,1),(2,3),(1,2),(0,1),(2,3),(1,2)
    k01_kernel<<<dim3(9216), dim3(256), 0, stream>>>(psi, u0pre, bsl + 0 * 1156);
    k123_kernel<<<dim3(12288), dim3(256), 0, stream>>>(psi, bsl + 1 * 1156, bsl + 2 * 1156,
                                                       nullptr, nullptr, nullptr);
    k01_kernel<<<dim3(9216), dim3(256), 0, stream>>>(psi, nullptr, bsl + 3 * 1156);
    k123_kernel<<<dim3(12288), dim3(256), 0, stream>>>(psi, bsl + 4 * 1156, bsl + 5 * 1156,
                                                       P1 + (size_t)(l * 4 + 1) * 144,
                                                       P1 + (size_t)(l * 4 + 2) * 144,
                                                       P1 + (size_t)(l * 4 + 3) * 144);
    // interferometer 2 (P1 on mode 0 rides along before its first BS(0,1))
    k01_kernel<<<dim3(9216), dim3(256), 0, stream>>>(psi, P1 + (size_t)(l * 4 + 0) * 144, bsl + 6 * 1156);
    k123_kernel<<<dim3(12288), dim3(256), 0, stream>>>(psi, bsl + 7 * 1156, bsl + 8 * 1156,
                                                       nullptr, nullptr, nullptr);
    k01_kernel<<<dim3(9216), dim3(256), 0, stream>>>(psi, nullptr, bsl + 9 * 1156);
    k123_kernel<<<dim3(12288), dim3(256), 0, stream>>>(psi, bsl + 10 * 1156, bsl + 11 * 1156,
                                                       P2 + (size_t)(l * 4 + 1) * 144,
                                                       P2 + (size_t)(l * 4 + 2) * 144,
                                                       P2 + (size_t)(l * 4 + 3) * 144);
  }
  // final pending mode-0 composite from layer 2
  k01_kernel<<<dim3(9216), dim3(256), 0, stream>>>(psi, P2 + (size_t)(1 * 4 + 0) * 144, nullptr);
  expval_kernel<<<dim3(1024), dim3(256), 0, stream>>>(psi, out);
}

// Round 2
// 2686.928 us; speedup vs baseline: 1.5129x; 1.5129x over previous
//
#include <hip/hip_runtime.h>
#include <math.h>

#define DD 12
#define D2 144
#define D3 1728
#define D4 20736
#define KP 18   // padded row stride for k01 tiles

typedef float2 c32;

__device__ __forceinline__ c32 cmul(c32 a, c32 b) {
  return make_float2(a.x * b.x - a.y * b.y, a.x * b.y + a.y * b.x);
}
__device__ __forceinline__ c32 cfma(c32 a, c32 b, c32 acc) {
  acc.x = fmaf(a.x, b.x, fmaf(-a.y, b.y, acc.x));
  acc.y = fmaf(a.x, b.y, fmaf(a.y, b.x, acc.y));
  return acc;
}
// extract c32 #n from an array of float4 (n must be compile-time after unroll)
__device__ __forceinline__ c32 get2(const float4* w, int n) {
  float4 q = w[n >> 1];
  return (n & 1) ? make_float2(q.z, q.w) : make_float2(q.x, q.y);
}
__device__ __forceinline__ float4 pack2(c32 a, c32 b) {
  return make_float4(a.x, a.y, b.x, b.y);
}

// sector offsets: secoff[N] = sum_{n<N} sz(n)^2, sz(n)=min(n,22-n,11)+1
__constant__ int d_secoff[23] = {0,1,5,14,30,55,91,140,204,285,385,506,650,
                                 771,871,952,1016,1065,1101,1126,1142,1151,1155};

struct RowMeta { int goff, sz, base, step; };
// metadata for output row r=(i,j) of the 144-pattern; addresses base+step*t stay in [0,143] for t in [0,12)
__device__ __forceinline__ RowMeta row_meta(int r) {
  int i = r / 12, j = r - i * 12, N = i + j;
  int sz = ((N <= 11) ? N : 22 - N) + 1;
  int lo = (N > 11) ? (N - 11) : 0;
  RowMeta m;
  m.goff = d_secoff[N] + (i - lo) * sz;
  m.sz = sz;
  m.base = (N <= 11) ? N : (N + 121);
  m.step = (N <= 11) ? 11 : -11;
  return m;
}

// ---------------- small matrix expm (LDS, 64-thread block) ----------------
__device__ void small_expm(c32* A, c32* S, c32* P, c32* T, float* red, int sz, int tid) {
  const int n2 = sz * sz;
  if (tid < sz) {
    float s = 0.f;
    for (int j = 0; j < sz; ++j) { c32 v = A[tid * sz + j]; s += sqrtf(fmaf(v.x, v.x, v.y * v.y)); }
    red[tid] = s;
  }
  __syncthreads();
  float nrm = 0.f;
  for (int i = 0; i < sz; ++i) nrm = fmaxf(nrm, red[i]);
  int sp = 0;
  while (nrm > 0.35f && sp < 24) { nrm *= 0.5f; ++sp; }
  const float scale = ldexpf(1.f, -sp);
  for (int e = tid; e < n2; e += 64) { A[e].x *= scale; A[e].y *= scale; }
  __syncthreads();
  for (int e = tid; e < n2; e += 64) {
    c32 a = A[e];
    P[e] = a;
    if ((e / sz) == (e % sz)) a.x += 1.f;
    S[e] = a;
  }
  __syncthreads();
  for (int k = 2; k <= 12; ++k) {
    const float inv = 1.f / (float)k;
    for (int e = tid; e < n2; e += 64) {
      int i = e / sz, j = e - i * sz;
      c32 acc = make_float2(0.f, 0.f);
      for (int q = 0; q < sz; ++q) acc = cfma(P[i * sz + q], A[q * sz + j], acc);
      acc.x *= inv; acc.y *= inv;
      T[e] = acc;
    }
    __syncthreads();
    for (int e = tid; e < n2; e += 64) {
      c32 t = T[e];
      P[e] = t;
      S[e].x += t.x; S[e].y += t.y;
    }
    __syncthreads();
  }
  for (int q = 0; q < sp; ++q) {
    for (int e = tid; e < n2; e += 64) {
      int i = e / sz, j = e - i * sz;
      c32 acc = make_float2(0.f, 0.f);
      for (int w = 0; w < sz; ++w) acc = cfma(S[i * sz + w], S[w * sz + j], acc);
      T[e] = acc;
    }
    __syncthreads();
    for (int e = tid; e < n2; e += 64) S[e] = T[e];
    __syncthreads();
  }
}

// ---------------- prep: per-batch displacement encoding (store col 0) ----------------
__global__ __launch_bounds__(64) void prep_disp(const float* __restrict__ x, c32* __restrict__ c0) {
  __shared__ c32 A[144], S[144], P[144], T[144];
  __shared__ float red[12];
  const int tid = threadIdx.x;
  const int b = blockIdx.x >> 2, m = blockIdx.x & 3;
  const float rr = x[b * 8 + m], ph = x[b * 8 + 4 + m];
  float sn, cs;
  sincosf(ph, &sn, &cs);
  const c32 alpha = make_float2(rr * cs, rr * sn);
  for (int e = tid; e < 144; e += 64) A[e] = make_float2(0.f, 0.f);
  __syncthreads();
  if (tid < 11) {
    float sq = sqrtf((float)(tid + 1));
    A[(tid + 1) * 12 + tid] = make_float2(alpha.x * sq, alpha.y * sq);   // alpha * adag
    A[tid * 12 + tid + 1] = make_float2(-alpha.x * sq, alpha.y * sq);    // -conj(alpha) * a
  }
  __syncthreads();
  small_expm(A, S, P, T, red, 12, tid);
  if (tid < 12) c0[(size_t)blockIdx.x * 12 + tid] = S[tid * 12];  // column 0
}

// ---------------- prep: beamsplitter sector blocks (direction-arranged compact) ----------------
__global__ __launch_bounds__(64) void prep_bs(const float* __restrict__ th1, const float* __restrict__ ph1,
                                              const float* __restrict__ th2, const float* __restrict__ ph2,
                                              c32* __restrict__ BS) {
  __shared__ c32 A[144], S[144], P[144], T[144];
  __shared__ float red[12];
  const int tid = threadIdx.x;
  const int g = blockIdx.x / 23, N = blockIdx.x % 23;
  const int l = g / 12, rem = g % 12, w = rem / 6, gi = rem % 6;
  const float th = (w ? th2 : th1)[l * 6 + gi];
  const float ph = (w ? ph2 : ph1)[l * 6 + gi];
  const int lo = (N > 11) ? (N - 11) : 0;
  const int sz = (N <= 11) ? (N + 1) : (23 - N);
  float sn, cs;
  sincosf(ph, &sn, &cs);
  for (int e = tid; e < sz * sz; e += 64) A[e] = make_float2(0.f, 0.f);
  __syncthreads();
  if (tid + 1 < sz) {
    int t = tid + 1;
    float s1 = th * sqrtf((float)((lo + t) * (N - lo - t + 1)));
    A[(t - 1) * sz + t] = make_float2(cs * s1, sn * s1);       //  th e^{i ph} sqrt(...)
    A[t * sz + t - 1] = make_float2(-cs * s1, sn * s1);        // -th e^{-i ph} sqrt(...)
  }
  __syncthreads();
  small_expm(A, S, P, T, red, sz, tid);
  // store with per-sector iteration direction: N<=11 forward, N>=12 reversed columns
  c32* dst = BS + (size_t)g * 1156 + d_secoff[N];
  const bool upSec = (N <= 11);
  for (int e = tid; e < sz * sz; e += 64) {
    int p = e / sz, q = e - p * sz;
    int qs = upSec ? q : (sz - 1 - q);
    dst[p * sz + q] = S[p * sz + qs];
  }
}

// ---------------- prep: per-mode composites P1 = S*R1, P2 = K*Disp*R2 ----------------
__global__ __launch_bounds__(64) void prep_p(const float* __restrict__ r_, const float* __restrict__ phir,
                                             const float* __restrict__ vphi1,
                                             const float* __restrict__ a_, const float* __restrict__ phia,
                                             const float* __restrict__ vphi2, const float* __restrict__ kk,
                                             c32* __restrict__ P1, c32* __restrict__ P2) {
  __shared__ c32 A[144], S[144], P[144], T[144];
  __shared__ float red[12];
  const int tid = threadIdx.x;
  const int which = blockIdx.x >> 3, lm = blockIdx.x & 7;
  for (int e = tid; e < 144; e += 64) A[e] = make_float2(0.f, 0.f);
  __syncthreads();
  if (which == 0) {
    const float rv = r_[lm], pv = phir[lm];
    float sn, cs;
    sincosf(pv, &sn, &cs);
    const c32 z = make_float2(rv * cs, rv * sn);
    if (tid < 10) {
      float sq = 0.5f * sqrtf((float)((tid + 1) * (tid + 2)));
      A[tid * 12 + tid + 2] = make_float2(z.x * sq, -z.y * sq);      // 0.5 conj(z) a^2
      A[(tid + 2) * 12 + tid] = make_float2(-z.x * sq, -z.y * sq);   // -0.5 z (a^2)^dag
    }
  } else {
    const float av = a_[lm], pv = phia[lm];
    float sn, cs;
    sincosf(pv, &sn, &cs);
    const c32 alpha = make_float2(av * cs, av * sn);
    if (tid < 11) {
      float sq = sqrtf((float)(tid + 1));
      A[(tid + 1) * 12 + tid] = make_float2(alpha.x * sq, alpha.y * sq);
      A[tid * 12 + tid + 1] = make_float2(-alpha.x * sq, alpha.y * sq);
    }
  }
  __syncthreads();
  small_expm(A, S, P, T, red, 12, tid);
  if (which == 0) {
    const float vp = vphi1[lm];
    for (int e = tid; e < 144; e += 64) {
      int j = e % 12;
      float sn, cs;
      sincosf(vp * (float)j, &sn, &cs);
      P1[(size_t)lm * 144 + e] = cmul(S[e], make_float2(cs, sn));
    }
  } else {
    const float vp = vphi2[lm], kv = kk[lm];
    for (int e = tid; e < 144; e += 64) {
      int i = e / 12, j = e % 12;
      float sn1, cs1, sn2, cs2;
      sincosf(vp * (float)j, &sn1, &cs1);
      float ang = kv * (float)i;  // match reference f32 eval order (k*n)*n
      ang *= (float)i;
      sincosf(ang, &sn2, &cs2);
      P2[(size_t)lm * 144 + e] = cmul(make_float2(cs2, sn2), cmul(S[e], make_float2(cs1, sn1)));
    }
  }
}

// ---------------- init: product state from displacement columns ----------------
__global__ __launch_bounds__(256) void init_psi(c32* __restrict__ psi, const c32* __restrict__ c0) {
  __shared__ c32 v[4][12];
  __shared__ c32 v01[144], v23[144];
  const int b = blockIdx.x, tid = threadIdx.x;
  if (tid < 48) v[tid / 12][tid % 12] = c0[(size_t)b * 48 + tid];
  __syncthreads();
  for (int e = tid; e < 144; e += 256) {
    v01[e] = cmul(v[0][e / 12], v[1][e % 12]);
    v23[e] = cmul(v[2][e / 12], v[3][e % 12]);
  }
  __syncthreads();
  c32* dst = psi + (size_t)b * D4;
  for (int e = tid; e < D4; e += 256) dst[e] = cmul(v01[e / 144], v23[e % 144]);
}

// ---------------- fused pass over modes {1,2,3}: BS(2,3) -> BS(1,2) -> U1 -> U2 -> U3 ----------------
// One slab (b,n0) of 1728 c32 per block. 144 worker threads own one pattern row each,
// batching the 12 spectator values in registers.
__global__ __launch_bounds__(256) void k123_kernel(
    c32* __restrict__ psi,
    const c32* __restrict__ gbs23, const c32* __restrict__ gbs12,
    const c32* __restrict__ gu1, const c32* __restrict__ gu2, const c32* __restrict__ gu3) {
  __shared__ c32 bufA[D3];
  __shared__ c32 bufB[D3];
  __shared__ c32 gA[1168], gBs[1168];   // compact BS gates (+pad for masked tail reads)
  __shared__ c32 gV1[144], gV2[144], gV3[144];
  const int tid = threadIdx.x;
  if (gbs23) for (int e = tid; e < 1156; e += 256) gA[e] = gbs23[e];
  if (gbs12) for (int e = tid; e < 1156; e += 256) gBs[e] = gbs12[e];
  if (gu1)   for (int e = tid; e < 144; e += 256) gV1[e] = gu1[e];
  if (gu2)   for (int e = tid; e < 144; e += 256) gV2[e] = gu2[e];
  if (gu3)   for (int e = tid; e < 144; e += 256) gV3[e] = gu3[e];
  c32* slab = psi + (size_t)blockIdx.x * D3;
  for (int v = tid; v < D3 / 2; v += 256) ((float4*)bufA)[v] = ((const float4*)slab)[v];
  __syncthreads();
  c32* cur = bufA;
  c32* nxt = bufB;
  const int r = tid;
  RowMeta m;
  if (r < 144) m = row_meta(r);

  if (gbs23) {  // spectator n1 (stride 144); gather stride +-11 within each 144-block
    if (r < 144) {
      c32 acc[12];
#pragma unroll
      for (int n = 0; n < 12; ++n) acc[n] = make_float2(0.f, 0.f);
      int a = m.base;
#pragma unroll
      for (int t = 0; t < 12; ++t) {
        c32 g = gA[m.goff + t];
        if (t >= m.sz) { g.x = 0.f; g.y = 0.f; }
#pragma unroll
        for (int n = 0; n < 12; ++n) acc[n] = cfma(g, cur[n * 144 + a], acc[n]);
        a += m.step;
      }
#pragma unroll
      for (int n = 0; n < 12; ++n) nxt[n * 144 + r] = acc[n];
    }
    __syncthreads();
    c32* t_ = cur; cur = nxt; nxt = t_;
  }
  if (gbs12) {  // spectator n3 (contiguous, b128-batched); row addresses = 12*pattern
    if (r < 144) {
      c32 acc[12];
#pragma unroll
      for (int n = 0; n < 12; ++n) acc[n] = make_float2(0.f, 0.f);
      int a = m.base * 12;
      const int st = m.step * 12;
#pragma unroll
      for (int t = 0; t < 12; ++t) {
        c32 g = gBs[m.goff + t];
        if (t >= m.sz) { g.x = 0.f; g.y = 0.f; }
        const float4* ip = (const float4*)(cur + a);
        float4 w[6];
#pragma unroll
        for (int q = 0; q < 6; ++q) w[q] = ip[q];
#pragma unroll
        for (int n = 0; n < 12; ++n) acc[n] = cfma(g, get2(w, n), acc[n]);
        a += st;
      }
      float4* op = (float4*)(nxt + r * 12);
#pragma unroll
      for (int q = 0; q < 6; ++q) op[q] = pack2(acc[2 * q], acc[2 * q + 1]);
    }
    __syncthreads();
    c32* t_ = cur; cur = nxt; nxt = t_;
  }
  if (gu1) {  // mode 1: out(i,n2,n3), thread r=(i,n2), batch n3
    if (r < 144) {
      const int i = r / 12, n2 = r - i * 12;
      float4 gr[6];
      const float4* gp = (const float4*)(gV1 + i * 12);
#pragma unroll
      for (int q = 0; q < 6; ++q) gr[q] = gp[q];
      c32 acc[12];
#pragma unroll
      for (int n = 0; n < 12; ++n) acc[n] = make_float2(0.f, 0.f);
#pragma unroll
      for (int j = 0; j < 12; ++j) {
        c32 g = get2(gr, j);
        const float4* ip = (const float4*)(cur + j * 144 + n2 * 12);
        float4 w[6];
#pragma unroll
        for (int q = 0; q < 6; ++q) w[q] = ip[q];
#pragma unroll
        for (int n = 0; n < 12; ++n) acc[n] = cfma(g, get2(w, n), acc[n]);
      }
      float4* op = (float4*)(nxt + i * 144 + n2 * 12);
#pragma unroll
      for (int q = 0; q < 6; ++q) op[q] = pack2(acc[2 * q], acc[2 * q + 1]);
    }
    __syncthreads();
    c32* t_ = cur; cur = nxt; nxt = t_;
  }
  if (gu2) {  // mode 2: out(n1,i,n3), thread r=(n1,i), batch n3
    if (r < 144) {
      const int n1 = r / 12, i = r - n1 * 12;
      float4 gr[6];
      const float4* gp = (const float4*)(gV2 + i * 12);
#pragma unroll
      for (int q = 0; q < 6; ++q) gr[q] = gp[q];
      c32 acc[12];
#pragma unroll
      for (int n = 0; n < 12; ++n) acc[n] = make_float2(0.f, 0.f);
#pragma unroll
      for (int j = 0; j < 12; ++j) {
        c32 g = get2(gr, j);
        const float4* ip = (const float4*)(cur + n1 * 144 + j * 12);
        float4 w[6];
#pragma unroll
        for (int q = 0; q < 6; ++q) w[q] = ip[q];
#pragma unroll
        for (int n = 0; n < 12; ++n) acc[n] = cfma(g, get2(w, n), acc[n]);
      }
      float4* op = (float4*)(nxt + n1 * 144 + i * 12);
#pragma unroll
      for (int q = 0; q < 6; ++q) op[q] = pack2(acc[2 * q], acc[2 * q + 1]);
    }
    __syncthreads();
    c32* t_ = cur; cur = nxt; nxt = t_;
  }
  if (gu3) {  // mode 3: out(n1,n2,i), thread r=(n1,n2), input row in registers
    if (r < 144) {
      float4 w[6];
      const float4* ip = (const float4*)(cur + r * 12);
#pragma unroll
      for (int q = 0; q < 6; ++q) w[q] = ip[q];
      c32 acc[12];
#pragma unroll
      for (int i = 0; i < 12; ++i) {
        float4 gi[6];
        const float4* gp = (const float4*)(gV3 + i * 12);
#pragma unroll
        for (int q = 0; q < 6; ++q) gi[q] = gp[q];
        c32 s = make_float2(0.f, 0.f);
#pragma unroll
        for (int j = 0; j < 12; ++j) s = cfma(get2(gi, j), get2(w, j), s);
        acc[i] = s;
      }
      float4* op = (float4*)(nxt + r * 12);
#pragma unroll
      for (int q = 0; q < 6; ++q) op[q] = pack2(acc[2 * q], acc[2 * q + 1]);
    }
    __syncthreads();
    c32* t_ = cur; cur = nxt; nxt = t_;
  }
  for (int v = tid; v < D3 / 2; v += 256) ((float4*)slab)[v] = ((const float4*)cur)[v];
}

// ---------------- fused pass over modes {0,1}: U0 -> BS(0,1) ----------------
// Tile = 144 (n0,n1)-rows x 16 (n2,n3)-columns, padded row stride KP=18 (bank spread).
__global__ __launch_bounds__(256) void k01_kernel(
    c32* __restrict__ psi, const c32* __restrict__ gu0, const c32* __restrict__ gbs) {
  __shared__ c32 bufA[D2 * KP];
  __shared__ c32 bufB[D2 * KP];
  __shared__ c32 gBs[1168], g0[144];
  const int tid = threadIdx.x;
  if (gbs) for (int e = tid; e < 1156; e += 256) gBs[e] = gbs[e];
  if (gu0) for (int e = tid; e < 144; e += 256) g0[e] = gu0[e];
  const int b = blockIdx.x / 9, tile = blockIdx.x % 9;
  c32* gbase = psi + (size_t)b * D4 + tile * 16;
  for (int e = tid; e < 144 * 8; e += 256) {
    int row = e >> 3, q = e & 7;
    ((float4*)(bufA + row * KP))[q] = ((const float4*)(gbase + (size_t)row * 144))[q];
  }
  __syncthreads();
  c32* cur = bufA;
  c32* nxt = bufB;
  const int r = tid;
  if (gu0) {  // out row (i,n1) = U0[i,j] * in row (j,n1)
    if (r < 144) {
      const int i = r / 12, n1 = r - i * 12;
      float4 gr[6];
      const float4* gp = (const float4*)(g0 + i * 12);
#pragma unroll
      for (int q = 0; q < 6; ++q) gr[q] = gp[q];
      c32 acc[16];
#pragma unroll
      for (int n = 0; n < 16; ++n) acc[n] = make_float2(0.f, 0.f);
#pragma unroll
      for (int j = 0; j < 12; ++j) {
        c32 g = get2(gr, j);
        const float4* ip = (const float4*)(cur + (j * 12 + n1) * KP);
        float4 w[8];
#pragma unroll
        for (int q = 0; q < 8; ++q) w[q] = ip[q];
#pragma unroll
        for (int n = 0; n < 16; ++n) acc[n] = cfma(g, get2(w, n), acc[n]);
      }
      float4* op = (float4*)(nxt + r * KP);
#pragma unroll
      for (int q = 0; q < 8; ++q) op[q] = pack2(acc[2 * q], acc[2 * q + 1]);
    }
    __syncthreads();
    c32* t_ = cur; cur = nxt; nxt = t_;
  }
  if (gbs) {  // block-sparse BS over (n0,n1) pattern rows
    RowMeta m;
    if (r < 144) m = row_meta(r);
    if (r < 144) {
      c32 acc[16];
#pragma unroll
      for (int n = 0; n < 16; ++n) acc[n] = make_float2(0.f, 0.f);
      int a = m.base;
#pragma unroll
      for (int t = 0; t < 12; ++t) {
        c32 g = gBs[m.goff + t];
        if (t >= m.sz) { g.x = 0.f; g.y = 0.f; }
        const float4* ip = (const float4*)(cur + a * KP);
        float4 w[8];
#pragma unroll
        for (int q = 0; q < 8; ++q) w[q] = ip[q];
#pragma unroll
        for (int n = 0; n < 16; ++n) acc[n] = cfma(g, get2(w, n), acc[n]);
        a += m.step;
      }
      float4* op = (float4*)(nxt + r * KP);
#pragma unroll
      for (int q = 0; q < 8; ++q) op[q] = pack2(acc[2 * q], acc[2 * q + 1]);
    }
    __syncthreads();
    c32* t_ = cur; cur = nxt; nxt = t_;
  }
  for (int e = tid; e < 144 * 8; e += 256) {
    int row = e >> 3, q = e & 7;
    ((float4*)(gbase + (size_t)row * 144))[q] = ((const float4*)(cur + row * KP))[q];
  }
}

// ---------------- expvals: <X_m> = sum 2*sqrt(n+1)*Re(conj(psi_n) psi_{n+1}) ----------------
__global__ __launch_bounds__(256) void expval_kernel(const c32* __restrict__ psi, float* __restrict__ out) {
  __shared__ float red[1024];
  __shared__ float sq2[12];
  const int tid = threadIdx.x, b = blockIdx.x;
  if (tid < 12) sq2[tid] = 2.f * sqrtf((float)(tid + 1));
  __syncthreads();
  const c32* base = psi + (size_t)b * D4;
  float a0 = 0.f, a1 = 0.f, a2 = 0.f, a3 = 0.f;
  for (int e = tid; e < D4; e += 256) {
    c32 p = base[e];
    int n3 = e % 12, t = e / 12;
    int n2 = t % 12; t /= 12;
    int n1 = t % 12, n0 = t / 12;
    if (n3 < 11) { c32 q = base[e + 1];    a3 = fmaf(sq2[n3], fmaf(p.x, q.x, p.y * q.y), a3); }
    if (n2 < 11) { c32 q = base[e + 12];   a2 = fmaf(sq2[n2], fmaf(p.x, q.x, p.y * q.y), a2); }
    if (n1 < 11) { c32 q = base[e + 144];  a1 = fmaf(sq2[n1], fmaf(p.x, q.x, p.y * q.y), a1); }
    if (n0 < 11) { c32 q = base[e + 1728]; a0 = fmaf(sq2[n0], fmaf(p.x, q.x, p.y * q.y), a0); }
  }
  red[tid * 4 + 0] = a0; red[tid * 4 + 1] = a1; red[tid * 4 + 2] = a2; red[tid * 4 + 3] = a3;
  __syncthreads();
  for (int s = 128; s > 0; s >>= 1) {
    if (tid < s) {
      red[tid * 4 + 0] += red[(tid + s) * 4 + 0];
      red[tid * 4 + 1] += red[(tid + s) * 4 + 1];
      red[tid * 4 + 2] += red[(tid + s) * 4 + 2];
      red[tid * 4 + 3] += red[(tid + s) * 4 + 3];
    }
    __syncthreads();
  }
  if (tid < 4) out[b * 4 + tid] = red[tid];
}

extern "C" void kernel_launch(void* const* d_in, const int* in_sizes, int n_in,
                              void* d_out, int out_size, void* d_ws, size_t ws_size,
                              hipStream_t stream) {
  const float* x      = (const float*)d_in[0];
  const float* theta1 = (const float*)d_in[1];
  const float* phi1   = (const float*)d_in[2];
  const float* vphi1  = (const float*)d_in[3];
  const float* r_     = (const float*)d_in[4];
  const float* phir   = (const float*)d_in[5];
  const float* theta2 = (const float*)d_in[6];
  const float* phi2   = (const float*)d_in[7];
  const float* vphi2  = (const float*)d_in[8];
  const float* a_     = (const float*)d_in[9];
  const float* phia   = (const float*)d_in[10];
  const float* kk     = (const float*)d_in[11];
  float* out = (float*)d_out;

  // workspace layout (bytes)
  const size_t PSI_OFF = 0;                              // 1024*20736*8 = 169,869,312
  const size_t C0_OFF  = 169869312;                      // 1024*4*12*8  =     393,216
  const size_t P1_OFF  = C0_OFF + 393216;                // 8*144*8      =       9,216
  const size_t P2_OFF  = P1_OFF + 9216;
  const size_t BS_OFF  = P2_OFF + 9216;                  // 24*1156*8    =     221,952
  const size_t NEED    = BS_OFF + 221952;
  if (ws_size < NEED) return;  // insufficient scratch; fail loudly in validation

  char* ws = (char*)d_ws;
  c32* psi = (c32*)(ws + PSI_OFF);
  c32* c0  = (c32*)(ws + C0_OFF);
  c32* P1  = (c32*)(ws + P1_OFF);
  c32* P2  = (c32*)(ws + P2_OFF);
  c32* BS  = (c32*)(ws + BS_OFF);

  prep_disp<<<dim3(4096), dim3(64), 0, stream>>>(x, c0);
  prep_bs<<<dim3(552), dim3(64), 0, stream>>>(theta1, phi1, theta2, phi2, BS);
  prep_p<<<dim3(16), dim3(64), 0, stream>>>(r_, phir, vphi1, a_, phia, vphi2, kk, P1, P2);
  init_psi<<<dim3(1024), dim3(256), 0, stream>>>(psi, c0);

  for (int l = 0; l < 2; ++l) {
    c32* bsl = BS + (size_t)l * 12 * 1156;
    const c32* u0pre = (l == 0) ? (const c32*)nullptr : (const c32*)(P2 + (size_t)(l - 1) * 4 * 144);
    // interferometer 1: BS order per Clements mesh: (0,1),(2,3),(1,2),(0,1),(2,3),(1,2)
    k01_kernel<<<dim3(9216), dim3(256), 0, stream>>>(psi, u0pre, bsl + 0 * 1156);
    k123_kernel<<<dim3(12288), dim3(256), 0, stream>>>(psi, bsl + 1 * 1156, bsl + 2 * 1156,
                                                       nullptr, nullptr, nullptr);
    k01_kernel<<<dim3(9216), dim3(256), 0, stream>>>(psi, nullptr, bsl + 3 * 1156);
    k123_kernel<<<dim3(12288), dim3(256), 0, stream>>>(psi, bsl + 4 * 1156, bsl + 5 * 1156,
                                                       P1 + (size_t)(l * 4 + 1) * 144,
                                                       P1 + (size_t)(l * 4 + 2) * 144,
                                                       P1 + (size_t)(l * 4 + 3) * 144);
    // interferometer 2 (P1 on mode 0 rides along before its first BS(0,1))
    k01_kernel<<<dim3(9216), dim3(256), 0, stream>>>(psi, P1 + (size_t)(l * 4 + 0) * 144, bsl + 6 * 1156);
    k123_kernel<<<dim3(12288), dim3(256), 0, stream>>>(psi, bsl + 7 * 1156, bsl + 8 * 1156,
                                                       nullptr, nullptr, nullptr);
    k01_kernel<<<dim3(9216), dim3(256), 0, stream>>>(psi, nullptr, bsl + 9 * 1156);
    k123_kernel<<<dim3(12288), dim3(256), 0, stream>>>(psi, bsl + 10 * 1156, bsl + 11 * 1156,
                                                       P2 + (size_t)(l * 4 + 1) * 144,
                                                       P2 + (size_t)(l * 4 + 2) * 144,
                                                       P2 + (size_t)(l * 4 + 3) * 144);
  }
  // final pending mode-0 composite from layer 2
  k01_kernel<<<dim3(9216), dim3(256), 0, stream>>>(psi, P2 + (size_t)(1 * 4 + 0) * 144, nullptr);
  expval_kernel<<<dim3(1024), dim3(256), 0, stream>>>(psi, out);
}